// Round 1
// baseline (155.927 us; speedup 1.0000x reference)
//
#include <hip/hip_runtime.h>
#include <stdint.h>

// DeformConv1d: x[8,256,4096] f32, offsets[8,1,4094,3] f32,
// weight[256,256,3] f32, bias[256] f32 -> out[8,256,4094] f32.
// Fused bf16-MFMA GEMM: out[b,o,t] = sum_{k,c} W[o,c,k]*interp[b,c,t,k] + bias[o]
// interp built on the fly from an LDS-staged contiguous x-window
// (T is clipped to [t, t+2] so a 128-t tile only needs x[t0 .. t0+130]).

constexpr int CIN  = 256;
constexpr int LX   = 4096;
constexpr int KT   = 3;
constexpr int OUTL = 4094;
constexpr int COUT = 256;
constexpr int BN   = 128;   // t per block
constexpr int WIN  = 134;   // padded LDS window row (need 132)
constexpr int APAD = 40;    // A tile row: 32 + 8 pad (avoids b128 phase collisions)

typedef __attribute__((ext_vector_type(8))) short bf16x8;
typedef __attribute__((ext_vector_type(4))) float f32x4;

__device__ __forceinline__ short f2bf(float f) {
  union { float f; uint32_t u; } v; v.f = f;
  uint32_t r = v.u + 0x7FFFu + ((v.u >> 16) & 1u);  // RNE
  return (short)(r >> 16);
}
__device__ __forceinline__ float bf2f(short s) {
  union { uint32_t u; float f; } v;
  v.u = ((uint32_t)(uint16_t)s) << 16;
  return v.f;
}

__global__ __launch_bounds__(512, 2) void deform_conv1d_kernel(
    const float* __restrict__ x, const float* __restrict__ off,
    const float* __restrict__ w, const float* __restrict__ bias,
    float* __restrict__ out) {

  // c-halved x window (keeps static LDS < 64KB): 128 x 134 bf16
  __shared__ short Xn[128][WIN];          // 34304 B
  __shared__ short At[COUT][APAD];        // 20480 B
  __shared__ float w0s[KT][BN];           //  1536 B
  __shared__ float w1s[KT][BN];           //  1536 B
  __shared__ int   d0s[KT][BN];           //  1536 B
  __shared__ float biasS[COUT];           //  1024 B   total 60416 B

  const int tid  = threadIdx.x;
  const int lane = tid & 63;
  const int wid  = tid >> 6;
  const int llo  = lane & 15;
  const int lhi  = lane >> 4;

  const int b  = blockIdx.x >> 5;   // 8 batches
  const int tt = blockIdx.x & 31;   // 32 t-tiles
  const int t0 = tt * BN;

  // ---- per-(t,k) meta: clipped sample position -> (delta0, w0, w1) ----
  for (int idx = tid; idx < KT * BN; idx += 512) {
    const int k  = idx >> 7;
    const int tl = idx & 127;
    const int t  = t0 + tl;
    float w0 = 0.f, w1 = 0.f; int d0 = 0;
    if (t < OUTL) {
      const float o = off[((size_t)b * OUTL + t) * KT + k];
      float T = (float)(t + k) + o;
      T = fminf(fmaxf(T, (float)t), (float)(t + 2));   // clip to [t, t+2]
      int U0 = (int)floorf(T);                          // >= 0 since T >= t
      if (U0 > LX - 2) U0 = LX - 2;
      w0 = fmaxf(0.f, 1.f - fabsf((float)U0 - T));
      w1 = fmaxf(0.f, 1.f - fabsf((float)(U0 + 1) - T));
      d0 = U0 - t0;                                     // in [0, 130]
    }
    w0s[k][tl] = w0; w1s[k][tl] = w1; d0s[k][tl] = d0;
  }
  for (int idx = tid; idx < COUT; idx += 512) biasS[idx] = bias[idx];

  const int wm = (wid >> 2) * 128;  // 2 wave-rows in M
  const int wn = (wid & 3) * 32;    // 4 wave-cols in N

  f32x4 acc[8][2];
  #pragma unroll
  for (int i = 0; i < 8; ++i) {
    acc[i][0] = (f32x4){0.f, 0.f, 0.f, 0.f};
    acc[i][1] = (f32x4){0.f, 0.f, 0.f, 0.f};
  }

  const float* xb = x + (size_t)b * CIN * LX;

  for (int ch = 0; ch < 2; ++ch) {            // c-halves: [0,128) and [128,256)
    // ---- stage x window half: x[b][c][t0 .. t0+131] -> bf16 (coalesced) ----
    for (int idx = tid; idx < 128 * 33; idx += 512) {
      const int cl = idx / 33, g = idx % 33;
      const int c  = ch * 128 + cl;
      const int l  = t0 + 4 * g;
      float f0 = 0.f, f1 = 0.f, f2v = 0.f, f3 = 0.f;
      if (l + 3 < LX) {
        const float4 v = *(const float4*)(xb + (size_t)c * LX + l);
        f0 = v.x; f1 = v.y; f2v = v.z; f3 = v.w;
      } else {
        const float* p = xb + (size_t)c * LX;
        if (l + 0 < LX) f0  = p[l + 0];
        if (l + 1 < LX) f1  = p[l + 1];
        if (l + 2 < LX) f2v = p[l + 2];
        if (l + 3 < LX) f3  = p[l + 3];
      }
      const uint32_t p0 = ((uint32_t)(uint16_t)f2bf(f1) << 16) | (uint16_t)f2bf(f0);
      const uint32_t p1 = ((uint32_t)(uint16_t)f2bf(f3) << 16) | (uint16_t)f2bf(f2v);
      *(uint32_t*)&Xn[cl][4 * g + 0] = p0;
      *(uint32_t*)&Xn[cl][4 * g + 2] = p1;
    }
    __syncthreads();  // window (and meta on first pass) visible

    for (int ks = 0; ks < 12; ++ks) {         // 12 K-chunks of 32 per half
      const int ktap = ks >> 2;               // tap 0..2 (fixed within chunk)
      const int c0l  = (ks & 3) * 32;         // local c base in Xn
      const int c0g  = ch * 128 + c0l;        // global c base

      // ---- A tile: At[o][kk] = bf16(weight[o][c0g+kk][ktap]) ----
      {
        const int kk4 = (tid & 7) * 4;
        const int ob  = tid >> 3;
        #pragma unroll
        for (int rep = 0; rep < 4; ++rep) {
          const int o = ob + rep * 64;
          const float* wp = w + ((size_t)o * CIN + (c0g + kk4)) * KT + ktap;
          const uint32_t p0 =
              ((uint32_t)(uint16_t)f2bf(wp[3]) << 16) | (uint16_t)f2bf(wp[0]);
          const uint32_t p1 =
              ((uint32_t)(uint16_t)f2bf(wp[9]) << 16) | (uint16_t)f2bf(wp[6]);
          *(uint32_t*)&At[o][kk4 + 0] = p0;
          *(uint32_t*)&At[o][kk4 + 2] = p1;
        }
      }
      __syncthreads();

      // ---- B fragments, built directly from the LDS window ----
      // lane holds B[k'=8*lhi+j][n=llo]: interp at c = c0+8*lhi+j, t = wn+jn*16+llo
      bf16x8 bfr[2];
      #pragma unroll
      for (int jn = 0; jn < 2; ++jn) {
        const int   tl = wn + jn * 16 + llo;
        const float w0 = w0s[ktap][tl];
        const float w1 = w1s[ktap][tl];
        const int   d0 = d0s[ktap][tl];
        const int   cb = c0l + 8 * lhi;
        #pragma unroll
        for (int j = 0; j < 8; ++j) {
          const float x0 = bf2f(Xn[cb + j][d0]);
          const float x1 = bf2f(Xn[cb + j][d0 + 1]);
          bfr[jn][j] = f2bf(w0 * x0 + w1 * x1);
        }
      }

      // ---- MFMA: 8 m-frags x 2 n-frags ----
      #pragma unroll
      for (int i = 0; i < 8; ++i) {
        const bf16x8 afr = *(const bf16x8*)&At[wm + i * 16 + llo][8 * lhi];
        acc[i][0] = __builtin_amdgcn_mfma_f32_16x16x32_bf16(afr, bfr[0], acc[i][0], 0, 0, 0);
        acc[i][1] = __builtin_amdgcn_mfma_f32_16x16x32_bf16(afr, bfr[1], acc[i][1], 0, 0, 0);
      }
      __syncthreads();  // before At (next ks) / Xn (next half) overwrite
    }
  }

  // ---- epilogue: D[row=(lane>>4)*4+r][col=lane&15], + bias ----
  const size_t obase = (size_t)b * COUT * OUTL;
  #pragma unroll
  for (int i = 0; i < 8; ++i) {
    const int orow = wm + i * 16 + 4 * lhi;
    #pragma unroll
    for (int jn = 0; jn < 2; ++jn) {
      const int t = t0 + wn + jn * 16 + llo;
      if (t < OUTL) {
        #pragma unroll
        for (int r = 0; r < 4; ++r) {
          out[obase + (size_t)(orow + r) * OUTL + t] = acc[i][jn][r] + biasS[orow + r];
        }
      }
    }
  }
}

extern "C" void kernel_launch(void* const* d_in, const int* in_sizes, int n_in,
                              void* d_out, int out_size, void* d_ws, size_t ws_size,
                              hipStream_t stream) {
  const float* x    = (const float*)d_in[0];
  const float* off  = (const float*)d_in[1];
  const float* wgt  = (const float*)d_in[2];
  const float* bias = (const float*)d_in[3];
  float* out = (float*)d_out;
  // 8 batches x 32 t-tiles = 256 blocks (1 per CU), 512 threads (8 waves)
  deform_conv1d_kernel<<<dim3(256), dim3(512), 0, stream>>>(x, off, wgt, bias, out);
}

// Round 2
// 107.791 us; speedup vs baseline: 1.4466x; 1.4466x over previous
//
#include <hip/hip_runtime.h>
#include <stdint.h>

// DeformConv1d: x[8,256,4096] f32, offsets[8,1,4094,3] f32,
// weight[256,256,3] f32, bias[256] f32 -> out[8,256,4094] f32.
//
// Two kernels:
//  1) pack_weights: weight -> bf16, MFMA-A-fragment order, into d_ws (L2-hot,
//     shared by all blocks). Removes per-K-step A staging + its 2 barriers.
//  2) deform_gemm: fused bf16-MFMA GEMM. B operand (bilinear interp of x)
//     built in registers from an LDS-staged contiguous x window
//     (T clipped to [t, t+2] => 128-t tile needs only x[t0 .. t0+130]).
//     Interp meta (w0,w1,d0) lives in statically-indexed registers.
//     K-loop has NO barriers (3 __syncthreads per block total).

constexpr int CIN  = 256;
constexpr int LX   = 4096;
constexpr int KT   = 3;
constexpr int OUTL = 4094;
constexpr int COUT = 256;
constexpr int BN   = 128;   // t per block
constexpr int WIN  = 134;   // padded LDS window row (need 132)
constexpr int NQ   = 24;    // K-chunks of 32 (2 c-halves x 3 taps x 4 c-subtiles)

typedef __attribute__((ext_vector_type(8))) short bf16x8;
typedef __attribute__((ext_vector_type(4))) float f32x4;

__device__ __forceinline__ short f2bf(float f) {
  union { float f; uint32_t u; } v; v.f = f;
  uint32_t r = v.u + 0x7FFFu + ((v.u >> 16) & 1u);  // RNE
  return (short)(r >> 16);
}
__device__ __forceinline__ float bf2f(short s) {
  union { uint32_t u; float f; } v;
  v.u = ((uint32_t)(uint16_t)s) << 16;
  return v.f;
}

// Apack[q][o][k'] with q = ch*12 + ks, ks -> (ktap=ks>>2, csub=ks&3),
// k' = 0..31 covering c = ch*128 + csub*32 + k'.  24*256*32 shorts = 384 KB.
__global__ __launch_bounds__(256) void pack_weights_kernel(
    const float* __restrict__ w, short* __restrict__ ap) {
  const int idx = blockIdx.x * 256 + threadIdx.x;   // one u32 = 2 shorts
  if (idx >= NQ * COUT * 32 / 2) return;
  const int s    = idx * 2;
  const int kp   = s & 31;
  const int o    = (s >> 5) & 255;
  const int q    = s >> 13;
  const int ch   = q / 12;
  const int ks   = q % 12;
  const int ktap = ks >> 2;
  const int c0   = ch * 128 + (ks & 3) * 32;
  const float f0 = w[((size_t)o * CIN + c0 + kp) * KT + ktap];
  const float f1 = w[((size_t)o * CIN + c0 + kp + 1) * KT + ktap];
  const uint32_t p = ((uint32_t)(uint16_t)f2bf(f1) << 16) | (uint16_t)f2bf(f0);
  *(uint32_t*)&ap[s] = p;
}

__global__ __launch_bounds__(512, 2) void deform_gemm_kernel(
    const float* __restrict__ x, const float* __restrict__ off,
    const short* __restrict__ ap, const float* __restrict__ bias,
    float* __restrict__ out) {

  __shared__ short Xn[128][WIN];   // 34304 B: one c-half of the x window, bf16
  __shared__ float biasS[COUT];    //  1024 B

  const int tid  = threadIdx.x;
  const int lane = tid & 63;
  const int wid  = tid >> 6;
  const int llo  = lane & 15;
  const int lhi  = lane >> 4;

  const int b  = blockIdx.x >> 5;   // 8 batches
  const int tt = blockIdx.x & 31;   // 32 t-tiles
  const int t0 = tt * BN;

  const int wm = (wid >> 2) * 128;  // 2 wave-rows in M
  const int wn = (wid & 3) * 32;    // 4 wave-cols in N

  // ---- per-lane interp meta in registers (statically indexed) ----
  float w0r[2][3], w1r[2][3];
  int   d0r[2][3];
  #pragma unroll
  for (int jn = 0; jn < 2; ++jn) {
    const int t = t0 + wn + jn * 16 + llo;
    #pragma unroll
    for (int k = 0; k < KT; ++k) {
      float w0 = 0.f, w1 = 0.f; int d0 = 0;
      if (t < OUTL) {
        const float o = off[((size_t)b * OUTL + t) * KT + k];
        float T = (float)(t + k) + o;
        T = fminf(fmaxf(T, (float)t), (float)(t + 2));  // clip to [t, t+2]
        int U0 = (int)T;                                 // floor (T >= 0)
        if (U0 > LX - 2) U0 = LX - 2;
        w1 = T - (float)U0;                              // in [0,1]
        w0 = 1.f - w1;
        d0 = U0 - t0;                                    // in [0, 130]
      }
      w0r[jn][k] = w0; w1r[jn][k] = w1; d0r[jn][k] = d0;
    }
  }
  for (int idx = tid; idx < COUT; idx += 512) biasS[idx] = bias[idx];

  f32x4 acc[8][2];
  #pragma unroll
  for (int i = 0; i < 8; ++i) {
    acc[i][0] = (f32x4){0.f, 0.f, 0.f, 0.f};
    acc[i][1] = (f32x4){0.f, 0.f, 0.f, 0.f};
  }

  const float* xb = x + (size_t)b * CIN * LX;

  #pragma unroll
  for (int ch = 0; ch < 2; ++ch) {            // c-halves: [0,128) and [128,256)
    if (ch) __syncthreads();                  // previous half's K-steps done
    // ---- stage x window half: x[b][c][t0 .. t0+131] -> bf16 (coalesced) ----
    for (int idx = tid; idx < 128 * 33; idx += 512) {
      const int cl = idx / 33, g = idx % 33;
      const int c  = ch * 128 + cl;
      const int l  = t0 + 4 * g;
      float f0 = 0.f, f1 = 0.f, f2v = 0.f, f3 = 0.f;
      if (l + 3 < LX) {
        const float4 v = *(const float4*)(xb + (size_t)c * LX + l);
        f0 = v.x; f1 = v.y; f2v = v.z; f3 = v.w;
      } else {
        const float* p = xb + (size_t)c * LX;
        if (l + 0 < LX) f0  = p[l + 0];
        if (l + 1 < LX) f1  = p[l + 1];
        if (l + 2 < LX) f2v = p[l + 2];
        if (l + 3 < LX) f3  = p[l + 3];
      }
      const uint32_t p0 = ((uint32_t)(uint16_t)f2bf(f1) << 16) | (uint16_t)f2bf(f0);
      const uint32_t p1 = ((uint32_t)(uint16_t)f2bf(f3) << 16) | (uint16_t)f2bf(f2v);
      *(uint32_t*)&Xn[cl][4 * g + 0] = p0;
      *(uint32_t*)&Xn[cl][4 * g + 2] = p1;
    }
    __syncthreads();  // window (and bias on first pass) visible

    #pragma unroll
    for (int ks = 0; ks < 12; ++ks) {         // NO barriers in here
      const int q    = ch * 12 + ks;
      const int ktap = ks >> 2;               // static -> meta stays in regs
      const int c0l  = (ks & 3) * 32;

      // ---- B fragments from the LDS window ----
      // lane holds B[k'=8*lhi+j][n=llo]: interp at c=c0l+8*lhi+j, t=wn+jn*16+llo
      bf16x8 bfr[2];
      #pragma unroll
      for (int jn = 0; jn < 2; ++jn) {
        const float w0 = w0r[jn][ktap];
        const float w1 = w1r[jn][ktap];
        const int   d0 = d0r[jn][ktap];
        const int   cb = c0l + 8 * lhi;
        #pragma unroll
        for (int j = 0; j < 8; ++j) {
          const float x0 = bf2f(Xn[cb + j][d0]);
          const float x1 = bf2f(Xn[cb + j][d0 + 1]);
          bfr[jn][j] = f2bf(w0 * x0 + w1 * x1);
        }
      }

      // ---- A fragments straight from L2-hot packed weights ----
      const short* apq = ap + (((size_t)q * COUT + wm) << 5) + (lhi << 3);
      #pragma unroll
      for (int i = 0; i < 8; ++i) {
        const bf16x8 afr = *(const bf16x8*)(apq + (size_t)(i * 16 + llo) * 32);
        acc[i][0] = __builtin_amdgcn_mfma_f32_16x16x32_bf16(afr, bfr[0], acc[i][0], 0, 0, 0);
        acc[i][1] = __builtin_amdgcn_mfma_f32_16x16x32_bf16(afr, bfr[1], acc[i][1], 0, 0, 0);
      }
    }
  }

  // ---- epilogue: D[row=4*lhi+r][col=llo], + bias ----
  const size_t obase = (size_t)b * COUT * OUTL;
  #pragma unroll
  for (int i = 0; i < 8; ++i) {
    const int orow = wm + i * 16 + 4 * lhi;
    #pragma unroll
    for (int jn = 0; jn < 2; ++jn) {
      const int t = t0 + wn + jn * 16 + llo;
      if (t < OUTL) {
        #pragma unroll
        for (int r = 0; r < 4; ++r) {
          out[obase + (size_t)(orow + r) * OUTL + t] = acc[i][jn][r] + biasS[orow + r];
        }
      }
    }
  }
}

extern "C" void kernel_launch(void* const* d_in, const int* in_sizes, int n_in,
                              void* d_out, int out_size, void* d_ws, size_t ws_size,
                              hipStream_t stream) {
  const float* x    = (const float*)d_in[0];
  const float* off  = (const float*)d_in[1];
  const float* wgt  = (const float*)d_in[2];
  const float* bias = (const float*)d_in[3];
  float* out  = (float*)d_out;
  short* ap   = (short*)d_ws;   // 24*256*32*2 = 393216 B of scratch

  // pack weights (runs each call; deterministic, ~3 us)
  pack_weights_kernel<<<dim3((NQ * COUT * 32 / 2 + 255) / 256), dim3(256), 0, stream>>>(wgt, ap);
  // 8 batches x 32 t-tiles = 256 blocks, 512 threads (8 waves)
  deform_gemm_kernel<<<dim3(256), dim3(512), 0, stream>>>(x, off, ap, bias, out);
}

// Round 3
// 104.383 us; speedup vs baseline: 1.4938x; 1.0326x over previous
//
#include <hip/hip_runtime.h>
#include <stdint.h>

// DeformConv1d: x[8,256,4096] f32, offsets[8,1,4094,3] f32,
// weight[256,256,3] f32, bias[256] f32 -> out[8,256,4094] f32.
//
// R3: occupancy fix. 1024-thread blocks (16 waves = 4 waves/SIMD, vs 2
// before), wave grid 2M x 8N (each wave: 128 M-rows x 16 t). Per-wave
// K-step work halves (1 B-fragment instead of 2). Grid stays 256 blocks
// (1/CU); no extra HBM/L2 traffic. f2bf -> round-half-up (cheaper).

constexpr int CIN  = 256;
constexpr int LX   = 4096;
constexpr int KT   = 3;
constexpr int OUTL = 4094;
constexpr int COUT = 256;
constexpr int BN   = 128;   // t per block
constexpr int WIN  = 134;   // padded LDS window row (need 132)
constexpr int NQ   = 24;    // K-chunks of 32 (2 c-halves x 3 taps x 4 c-subtiles)

typedef __attribute__((ext_vector_type(8))) short bf16x8;
typedef __attribute__((ext_vector_type(4))) float f32x4;

__device__ __forceinline__ short f2bf(float f) {        // round-half-up
  union { float f; uint32_t u; } v; v.f = f;
  return (short)((v.u + 0x8000u) >> 16);
}
__device__ __forceinline__ uint32_t pack_bf2(float flo, float fhi) {
  union { float f; uint32_t u; } a, b; a.f = flo; b.f = fhi;
  return ((a.u + 0x8000u) >> 16) | ((b.u + 0x8000u) & 0xFFFF0000u);
}
__device__ __forceinline__ float bf2f(short s) {
  union { uint32_t u; float f; } v;
  v.u = ((uint32_t)(uint16_t)s) << 16;
  return v.f;
}

// Apack[q][o][k'] with q = ch*12 + ks, ks -> (ktap=ks>>2, csub=ks&3),
// k' = 0..31 covering c = ch*128 + csub*32 + k'.  24*256*32 shorts = 384 KB.
__global__ __launch_bounds__(256) void pack_weights_kernel(
    const float* __restrict__ w, short* __restrict__ ap) {
  const int idx = blockIdx.x * 256 + threadIdx.x;   // one u32 = 2 shorts
  if (idx >= NQ * COUT * 32 / 2) return;
  const int s    = idx * 2;
  const int kp   = s & 31;
  const int o    = (s >> 5) & 255;
  const int q    = s >> 13;
  const int ch   = q / 12;
  const int ks   = q % 12;
  const int ktap = ks >> 2;
  const int c0   = ch * 128 + (ks & 3) * 32;
  const float f0 = w[((size_t)o * CIN + c0 + kp) * KT + ktap];
  const float f1 = w[((size_t)o * CIN + c0 + kp + 1) * KT + ktap];
  *(uint32_t*)&ap[s] = pack_bf2(f0, f1);
}

__global__ __launch_bounds__(1024, 4) void deform_gemm_kernel(
    const float* __restrict__ x, const float* __restrict__ off,
    const short* __restrict__ ap, const float* __restrict__ bias,
    float* __restrict__ out) {

  __shared__ short Xn[128][WIN];   // 34304 B: one c-half of the x window, bf16
  __shared__ float biasS[COUT];    //  1024 B

  const int tid  = threadIdx.x;
  const int lane = tid & 63;
  const int wid  = tid >> 6;       // 0..15
  const int llo  = lane & 15;
  const int lhi  = lane >> 4;

  const int b  = blockIdx.x >> 5;   // 8 batches
  const int tt = blockIdx.x & 31;   // 32 t-tiles
  const int t0 = tt * BN;

  const int wm = (wid >> 3) * 128;  // 2 wave-rows in M (128 rows each)
  const int wn = (wid & 7) * 16;    // 8 wave-cols in N (16 t each)

  // ---- per-lane interp meta in registers (statically indexed) ----
  float w0r[3], w1r[3];
  int   d0r[3];
  {
    const int t = t0 + wn + llo;
    #pragma unroll
    for (int k = 0; k < KT; ++k) {
      float w0 = 0.f, w1 = 0.f; int d0 = 0;
      if (t < OUTL) {
        const float o = off[((size_t)b * OUTL + t) * KT + k];
        float T = (float)(t + k) + o;
        T = fminf(fmaxf(T, (float)t), (float)(t + 2));  // clip to [t, t+2]
        int U0 = (int)T;                                 // floor (T >= 0)
        if (U0 > LX - 2) U0 = LX - 2;
        w1 = T - (float)U0;                              // in [0,1]
        w0 = 1.f - w1;
        d0 = U0 - t0;                                    // in [0, 130]
      }
      w0r[k] = w0; w1r[k] = w1; d0r[k] = d0;
    }
  }
  if (tid < COUT) biasS[tid] = bias[tid];

  f32x4 acc[8];
  #pragma unroll
  for (int i = 0; i < 8; ++i) acc[i] = (f32x4){0.f, 0.f, 0.f, 0.f};

  const float* xb = x + (size_t)b * CIN * LX;

  #pragma unroll
  for (int ch = 0; ch < 2; ++ch) {            // c-halves: [0,128) and [128,256)
    if (ch) __syncthreads();                  // previous half's K-steps done
    // ---- stage x window half: x[b][c][t0 .. t0+131] -> bf16 (coalesced) ----
    for (int idx = tid; idx < 128 * 33; idx += 1024) {
      const int cl = idx / 33, g = idx % 33;
      const int c  = ch * 128 + cl;
      const int l  = t0 + 4 * g;
      float f0 = 0.f, f1 = 0.f, f2v = 0.f, f3 = 0.f;
      if (l + 3 < LX) {
        const float4 v = *(const float4*)(xb + (size_t)c * LX + l);
        f0 = v.x; f1 = v.y; f2v = v.z; f3 = v.w;
      } else {
        const float* p = xb + (size_t)c * LX;
        if (l + 0 < LX) f0  = p[l + 0];
        if (l + 1 < LX) f1  = p[l + 1];
        if (l + 2 < LX) f2v = p[l + 2];
        if (l + 3 < LX) f3  = p[l + 3];
      }
      *(uint32_t*)&Xn[cl][4 * g + 0] = pack_bf2(f0, f1);
      *(uint32_t*)&Xn[cl][4 * g + 2] = pack_bf2(f2v, f3);
    }
    __syncthreads();  // window (and bias on first pass) visible

    #pragma unroll
    for (int ks = 0; ks < 12; ++ks) {         // NO barriers in here
      const int q    = ch * 12 + ks;
      const int ktap = ks >> 2;               // static -> meta stays in regs
      const int c0l  = (ks & 3) * 32;

      // ---- B fragment from the LDS window ----
      // lane holds B[k'=8*lhi+j][n=llo]: interp at c=c0l+8*lhi+j, t=wn+llo
      const float w0 = w0r[ktap];
      const float w1 = w1r[ktap];
      const int   d0 = d0r[ktap];
      const int   cb = c0l + 8 * lhi;
      uint32_t bw[4];
      #pragma unroll
      for (int jj = 0; jj < 4; ++jj) {
        const float xa0 = bf2f(Xn[cb + 2 * jj + 0][d0]);
        const float xa1 = bf2f(Xn[cb + 2 * jj + 0][d0 + 1]);
        const float xb0 = bf2f(Xn[cb + 2 * jj + 1][d0]);
        const float xb1 = bf2f(Xn[cb + 2 * jj + 1][d0 + 1]);
        bw[jj] = pack_bf2(w0 * xa0 + w1 * xa1, w0 * xb0 + w1 * xb1);
      }
      const bf16x8 bfr = *(const bf16x8*)bw;

      // ---- A fragments straight from L2-hot packed weights ----
      const short* apq = ap + (((size_t)q * COUT + wm) << 5) + (lhi << 3);
      #pragma unroll
      for (int i = 0; i < 8; ++i) {
        const bf16x8 afr = *(const bf16x8*)(apq + (size_t)(i * 16 + llo) * 32);
        acc[i] = __builtin_amdgcn_mfma_f32_16x16x32_bf16(afr, bfr, acc[i], 0, 0, 0);
      }
    }
  }

  // ---- epilogue: D[row=4*lhi+r][col=llo], + bias ----
  const size_t obase = (size_t)b * COUT * OUTL;
  const int t = t0 + wn + llo;
  if (t < OUTL) {
    #pragma unroll
    for (int i = 0; i < 8; ++i) {
      const int orow = wm + i * 16 + 4 * lhi;
      #pragma unroll
      for (int r = 0; r < 4; ++r) {
        out[obase + (size_t)(orow + r) * OUTL + t] = acc[i][r] + biasS[orow + r];
      }
    }
  }
}

extern "C" void kernel_launch(void* const* d_in, const int* in_sizes, int n_in,
                              void* d_out, int out_size, void* d_ws, size_t ws_size,
                              hipStream_t stream) {
  const float* x    = (const float*)d_in[0];
  const float* off  = (const float*)d_in[1];
  const float* wgt  = (const float*)d_in[2];
  const float* bias = (const float*)d_in[3];
  float* out  = (float*)d_out;
  short* ap   = (short*)d_ws;   // 24*256*32*2 = 393216 B of scratch

  // pack weights (runs each call; deterministic, ~3 us)
  pack_weights_kernel<<<dim3((NQ * COUT * 32 / 2 + 255) / 256), dim3(256), 0, stream>>>(wgt, ap);
  // 8 batches x 32 t-tiles = 256 blocks, 1024 threads (16 waves, 4/SIMD)
  deform_gemm_kernel<<<dim3(256), dim3(1024), 0, stream>>>(x, off, ap, bias, out);
}

// Round 5
// 88.418 us; speedup vs baseline: 1.7635x; 1.1806x over previous
//
#include <hip/hip_runtime.h>
#include <stdint.h>

// DeformConv1d: x[8,256,4096] f32, offsets[8,1,4094,3] f32,
// weight[256,256,3] f32, bias[256] f32 -> out[8,256,4094] f32.
//
// R5: R4's transposed-window structure (B-fragment = 2 x ds_read_b128
// instead of 16 scalar ds_read_u16) with R3's PROVEN conversion code.
// R4's NaN suspects (cvt_pk inline asm, u32-typed LDS loads, packed f32
// math) are all reverted; this bisects structure vs micro-ops.

constexpr int CIN  = 256;
constexpr int LX   = 4096;
constexpr int KT   = 3;
constexpr int OUTL = 4094;
constexpr int COUT = 256;
constexpr int BN   = 128;   // t per block
constexpr int WPOS = 132;   // window positions staged (t0 .. t0+131)
constexpr int NQ   = 24;    // K-chunks of 32 (2 c-halves x 3 taps x 4 c-subtiles)

typedef __attribute__((ext_vector_type(8))) short bf16x8;
typedef __attribute__((ext_vector_type(4))) float f32x4;

__device__ __forceinline__ short f2bf(float f) {        // round-half-up
  union { float f; uint32_t u; } v; v.f = f;
  return (short)((v.u + 0x8000u) >> 16);
}
__device__ __forceinline__ uint32_t pack_bf2(float flo, float fhi) {
  union { float f; uint32_t u; } a, b; a.f = flo; b.f = fhi;
  return ((a.u + 0x8000u) >> 16) | ((b.u + 0x8000u) & 0xFFFF0000u);
}
__device__ __forceinline__ float bf2f(short s) {
  union { uint32_t u; float f; } v;
  v.u = ((uint32_t)(uint16_t)s) << 16;
  return v.f;
}

// Apack[q][o][k'] with q = ch*12 + ks, ks -> (ktap=ks>>2, csub=ks&3),
// k' = 0..31 covering c = ch*128 + csub*32 + k'.  24*256*32 shorts = 384 KB.
__global__ __launch_bounds__(256) void pack_weights_kernel(
    const float* __restrict__ w, short* __restrict__ ap) {
  const int idx = blockIdx.x * 256 + threadIdx.x;   // one u32 = 2 shorts
  if (idx >= NQ * COUT * 32 / 2) return;
  const int s    = idx * 2;
  const int kp   = s & 31;
  const int o    = (s >> 5) & 255;
  const int q    = s >> 13;
  const int ch   = q / 12;
  const int ks   = q % 12;
  const int ktap = ks >> 2;
  const int c0   = ch * 128 + (ks & 3) * 32;
  const float f0 = w[((size_t)o * CIN + c0 + kp) * KT + ktap];
  const float f1 = w[((size_t)o * CIN + c0 + kp + 1) * KT + ktap];
  *(uint32_t*)&ap[s] = pack_bf2(f0, f1);
}

__global__ __launch_bounds__(1024, 4) void deform_gemm_kernel(
    const float* __restrict__ x, const float* __restrict__ off,
    const short* __restrict__ ap, const float* __restrict__ bias,
    float* __restrict__ out) {

  // transposed window: Xt[pos][c] (one c-half), row = 128 shorts (pow2),
  // short-index swizzle: idx = pos*128 + c, idx ^= (pos&7)<<3  (16B granule)
  __shared__ short Xt[WPOS * 128];   // 33792 B
  __shared__ float biasS[COUT];      //  1024 B

  const int tid  = threadIdx.x;
  const int lane = tid & 63;
  const int wid  = tid >> 6;       // 0..15
  const int llo  = lane & 15;
  const int lhi  = lane >> 4;

  const int b  = blockIdx.x >> 5;   // 8 batches
  const int tt = blockIdx.x & 31;   // 32 t-tiles
  const int t0 = tt * BN;

  const int wm = (wid >> 3) * 128;  // 2 wave-rows in M (128 rows each)
  const int wn = (wid & 7) * 16;    // 8 wave-cols in N (16 t each)

  // ---- per-lane interp meta in registers (statically indexed) ----
  float w0r[3], w1r[3];
  int   d0r[3];
  {
    const int t = t0 + wn + llo;
    #pragma unroll
    for (int k = 0; k < KT; ++k) {
      float w0 = 0.f, w1 = 0.f; int d0 = 0;
      if (t < OUTL) {
        const float o = off[((size_t)b * OUTL + t) * KT + k];
        float T = (float)(t + k) + o;
        T = fminf(fmaxf(T, (float)t), (float)(t + 2));  // clip to [t, t+2]
        int U0 = (int)T;                                 // floor (T >= 0)
        if (U0 > LX - 2) U0 = LX - 2;
        w1 = T - (float)U0;                              // in [0,1]
        w0 = 1.f - w1;
        d0 = U0 - t0;                                    // in [0, 130]
      }
      w0r[k] = w0; w1r[k] = w1; d0r[k] = d0;
    }
  }
  if (tid < COUT) biasS[tid] = bias[tid];

  f32x4 acc[8];
  #pragma unroll
  for (int i = 0; i < 8; ++i) acc[i] = (f32x4){0.f, 0.f, 0.f, 0.f};

  const float* xb = x + (size_t)b * CIN * LX;

  #pragma unroll
  for (int ch = 0; ch < 2; ++ch) {            // c-halves: [0,128) and [128,256)
    if (ch) __syncthreads();                  // previous half's K-steps done
    // ---- stage x window half, transposed ----
    // lanes run along pos (= l): coalesced dword global reads; swizzled
    // scalar u16 LDS writes.
    #pragma unroll
    for (int rep = 0; rep < 17; ++rep) {
      const int idx = rep * 1024 + tid;
      if (idx < 128 * WPOS) {
        const int c   = idx / WPOS;
        const int pos = idx - c * WPOS;
        const int l   = t0 + pos;
        const float f = (l < LX) ? xb[(size_t)(ch * 128 + c) * LX + l] : 0.f;
        const int wi  = (pos * 128 + c) ^ ((pos & 7) << 3);
        Xt[wi] = f2bf(f);
      }
    }
    __syncthreads();  // window (and bias on first pass) visible

    #pragma unroll
    for (int ks = 0; ks < 12; ++ks) {         // NO barriers in here
      const int q    = ch * 12 + ks;
      const int ktap = ks >> 2;               // static -> meta stays in regs
      const int c0l  = (ks & 3) * 32;

      // ---- B fragment: 2 x ds_read_b128 from the transposed window ----
      // lane holds B[k'=8*lhi+j][n=llo]: interp at c=cb+j, t=wn+llo
      const float w0 = w0r[ktap];
      const float w1 = w1r[ktap];
      const int   d0 = d0r[ktap];
      const int   cb = c0l + 8 * lhi;               // multiple of 8
      const int   i0 = (d0 * 128 + cb) ^ ((d0 & 7) << 3);
      const int   i1 = ((d0 + 1) * 128 + cb) ^ (((d0 + 1) & 7) << 3);
      const bf16x8 r0 = *(const bf16x8*)&Xt[i0];
      const bf16x8 r1 = *(const bf16x8*)&Xt[i1];
      bf16x8 bfr;
      #pragma unroll
      for (int j = 0; j < 8; ++j) {
        bfr[j] = f2bf(bf2f(r0[j]) * w0 + bf2f(r1[j]) * w1);
      }

      // ---- A fragments straight from L1/L2-hot packed weights ----
      const short* apq = ap + (((size_t)q * COUT + wm) << 5) + (lhi << 3);
      #pragma unroll
      for (int i = 0; i < 8; ++i) {
        const bf16x8 afr = *(const bf16x8*)(apq + (size_t)(i * 16 + llo) * 32);
        acc[i] = __builtin_amdgcn_mfma_f32_16x16x32_bf16(afr, bfr, acc[i], 0, 0, 0);
      }
    }
  }

  // ---- epilogue: D[row=4*lhi+r][col=llo], + bias ----
  const size_t obase = (size_t)b * COUT * OUTL;
  const int t = t0 + wn + llo;
  if (t < OUTL) {
    #pragma unroll
    for (int i = 0; i < 8; ++i) {
      const int orow = wm + i * 16 + 4 * lhi;
      #pragma unroll
      for (int r = 0; r < 4; ++r) {
        out[obase + (size_t)(orow + r) * OUTL + t] = acc[i][r] + biasS[orow + r];
      }
    }
  }
}

extern "C" void kernel_launch(void* const* d_in, const int* in_sizes, int n_in,
                              void* d_out, int out_size, void* d_ws, size_t ws_size,
                              hipStream_t stream) {
  const float* x    = (const float*)d_in[0];
  const float* off  = (const float*)d_in[1];
  const float* wgt  = (const float*)d_in[2];
  const float* bias = (const float*)d_in[3];
  float* out  = (float*)d_out;
  short* ap   = (short*)d_ws;   // 24*256*32*2 = 393216 B of scratch

  // pack weights (runs each call; deterministic, ~3 us)
  pack_weights_kernel<<<dim3((NQ * COUT * 32 / 2 + 255) / 256), dim3(256), 0, stream>>>(wgt, ap);
  // 8 batches x 32 t-tiles = 256 blocks, 1024 threads (16 waves, 4/SIMD)
  deform_gemm_kernel<<<dim3(256), dim3(1024), 0, stream>>>(x, off, ap, bias, out);
}

// Round 6
// 87.689 us; speedup vs baseline: 1.7782x; 1.0083x over previous
//
#include <hip/hip_runtime.h>
#include <stdint.h>

// DeformConv1d: x[8,256,4096] f32, offsets[8,1,4094,3] f32,
// weight[256,256,3] f32, bias[256] f32 -> out[8,256,4094] f32.
//
// R6: occupancy/overlap fix on top of R5's proven transposed-window GEMM.
// BN 128 -> 64: grid 512 blocks (2 blocks/CU resident), 512-thread blocks
// (8 waves, 2M x 4N). launch_bounds(512,4) -> VGPR cap 128 so the compiler
// can keep the 8 per-K-step A-loads in flight. Cross-block overlap hides
// staging barriers + A-load L2 latency (R5: 1 block/CU, VGPR=64, all
// pipes <20% busy).

constexpr int CIN  = 256;
constexpr int LX   = 4096;
constexpr int KT   = 3;
constexpr int OUTL = 4094;
constexpr int COUT = 256;
constexpr int BN   = 64;    // t per block
constexpr int WPOS = 68;    // window positions staged (need t0 .. t0+66)
constexpr int NQ   = 24;    // K-chunks of 32 (2 c-halves x 3 taps x 4 c-subtiles)

typedef __attribute__((ext_vector_type(8))) short bf16x8;
typedef __attribute__((ext_vector_type(4))) float f32x4;

__device__ __forceinline__ short f2bf(float f) {        // round-half-up
  union { float f; uint32_t u; } v; v.f = f;
  return (short)((v.u + 0x8000u) >> 16);
}
__device__ __forceinline__ uint32_t pack_bf2(float flo, float fhi) {
  union { float f; uint32_t u; } a, b; a.f = flo; b.f = fhi;
  return ((a.u + 0x8000u) >> 16) | ((b.u + 0x8000u) & 0xFFFF0000u);
}
__device__ __forceinline__ float bf2f(short s) {
  union { uint32_t u; float f; } v;
  v.u = ((uint32_t)(uint16_t)s) << 16;
  return v.f;
}

// Apack[q][o][k'] with q = ch*12 + ks, ks -> (ktap=ks>>2, csub=ks&3),
// k' = 0..31 covering c = ch*128 + csub*32 + k'.  24*256*32 shorts = 384 KB.
__global__ __launch_bounds__(256) void pack_weights_kernel(
    const float* __restrict__ w, short* __restrict__ ap) {
  const int idx = blockIdx.x * 256 + threadIdx.x;   // one u32 = 2 shorts
  if (idx >= NQ * COUT * 32 / 2) return;
  const int s    = idx * 2;
  const int kp   = s & 31;
  const int o    = (s >> 5) & 255;
  const int q    = s >> 13;
  const int ch   = q / 12;
  const int ks   = q % 12;
  const int ktap = ks >> 2;
  const int c0   = ch * 128 + (ks & 3) * 32;
  const float f0 = w[((size_t)o * CIN + c0 + kp) * KT + ktap];
  const float f1 = w[((size_t)o * CIN + c0 + kp + 1) * KT + ktap];
  *(uint32_t*)&ap[s] = pack_bf2(f0, f1);
}

__global__ __launch_bounds__(512, 4) void deform_gemm_kernel(
    const float* __restrict__ x, const float* __restrict__ off,
    const short* __restrict__ ap, const float* __restrict__ bias,
    float* __restrict__ out) {

  // transposed window: Xt[pos][c] (one c-half), row = 128 shorts (pow2),
  // short-index swizzle: idx = pos*128 + c, idx ^= (pos&7)<<3  (16B granule)
  __shared__ short Xt[WPOS * 128];   // 17408 B
  __shared__ float biasS[COUT];      //  1024 B

  const int tid  = threadIdx.x;
  const int lane = tid & 63;
  const int wid  = tid >> 6;       // 0..7
  const int llo  = lane & 15;
  const int lhi  = lane >> 4;

  const int b  = blockIdx.x >> 6;   // 8 batches
  const int tt = blockIdx.x & 63;   // 64 t-tiles
  const int t0 = tt * BN;

  const int wm = (wid >> 2) * 128;  // 2 wave-rows in M (128 rows each)
  const int wn = (wid & 3) * 16;    // 4 wave-cols in N (16 t each)

  // ---- per-lane interp meta in registers (statically indexed) ----
  float w0r[3], w1r[3];
  int   d0r[3];
  {
    const int t = t0 + wn + llo;
    #pragma unroll
    for (int k = 0; k < KT; ++k) {
      float w0 = 0.f, w1 = 0.f; int d0 = 0;
      if (t < OUTL) {
        const float o = off[((size_t)b * OUTL + t) * KT + k];
        float T = (float)(t + k) + o;
        T = fminf(fmaxf(T, (float)t), (float)(t + 2));  // clip to [t, t+2]
        int U0 = (int)T;                                 // floor (T >= 0)
        if (U0 > LX - 2) U0 = LX - 2;
        w1 = T - (float)U0;                              // in [0,1]
        w0 = 1.f - w1;
        d0 = U0 - t0;                                    // in [0, 66]
      }
      w0r[k] = w0; w1r[k] = w1; d0r[k] = d0;
    }
  }
  if (tid < COUT) biasS[tid] = bias[tid];

  f32x4 acc[8];
  #pragma unroll
  for (int i = 0; i < 8; ++i) acc[i] = (f32x4){0.f, 0.f, 0.f, 0.f};

  const float* xb = x + (size_t)b * CIN * LX;

  #pragma unroll
  for (int ch = 0; ch < 2; ++ch) {            // c-halves: [0,128) and [128,256)
    if (ch) __syncthreads();                  // previous half's K-steps done
    // ---- stage x window half, transposed ----
    // lanes run along pos (= l): coalesced dword global reads; swizzled
    // scalar u16 LDS writes.  128*68 = 8704 = 17 * 512 exactly.
    #pragma unroll
    for (int rep = 0; rep < 17; ++rep) {
      const int idx = rep * 512 + tid;
      const int c   = idx / WPOS;
      const int pos = idx - c * WPOS;
      const int l   = t0 + pos;
      const float f = (l < LX) ? xb[(size_t)(ch * 128 + c) * LX + l] : 0.f;
      const int wi  = (pos * 128 + c) ^ ((pos & 7) << 3);
      Xt[wi] = f2bf(f);
    }
    __syncthreads();  // window (and bias on first pass) visible

    #pragma unroll
    for (int ks = 0; ks < 12; ++ks) {         // NO barriers in here
      const int q    = ch * 12 + ks;
      const int ktap = ks >> 2;               // static -> meta stays in regs
      const int c0l  = (ks & 3) * 32;

      // ---- B fragment: 2 x ds_read_b128 from the transposed window ----
      // lane holds B[k'=8*lhi+j][n=llo]: interp at c=cb+j, t=wn+llo
      const float w0 = w0r[ktap];
      const float w1 = w1r[ktap];
      const int   d0 = d0r[ktap];
      const int   cb = c0l + 8 * lhi;               // multiple of 8
      const int   i0 = (d0 * 128 + cb) ^ ((d0 & 7) << 3);
      const int   i1 = ((d0 + 1) * 128 + cb) ^ (((d0 + 1) & 7) << 3);
      const bf16x8 r0 = *(const bf16x8*)&Xt[i0];
      const bf16x8 r1 = *(const bf16x8*)&Xt[i1];
      bf16x8 bfr;
      #pragma unroll
      for (int j = 0; j < 8; ++j) {
        bfr[j] = f2bf(bf2f(r0[j]) * w0 + bf2f(r1[j]) * w1);
      }

      // ---- A fragments straight from L1/L2-hot packed weights ----
      const short* apq = ap + (((size_t)q * COUT + wm) << 5) + (lhi << 3);
      #pragma unroll
      for (int i = 0; i < 8; ++i) {
        const bf16x8 afr = *(const bf16x8*)(apq + (size_t)(i * 16 + llo) * 32);
        acc[i] = __builtin_amdgcn_mfma_f32_16x16x32_bf16(afr, bfr, acc[i], 0, 0, 0);
      }
    }
  }

  // ---- epilogue: D[row=4*lhi+r][col=llo], + bias ----
  const size_t obase = (size_t)b * COUT * OUTL;
  const int t = t0 + wn + llo;
  if (t < OUTL) {
    #pragma unroll
    for (int i = 0; i < 8; ++i) {
      const int orow = wm + i * 16 + 4 * lhi;
      #pragma unroll
      for (int r = 0; r < 4; ++r) {
        out[obase + (size_t)(orow + r) * OUTL + t] = acc[i][r] + biasS[orow + r];
      }
    }
  }
}

extern "C" void kernel_launch(void* const* d_in, const int* in_sizes, int n_in,
                              void* d_out, int out_size, void* d_ws, size_t ws_size,
                              hipStream_t stream) {
  const float* x    = (const float*)d_in[0];
  const float* off  = (const float*)d_in[1];
  const float* wgt  = (const float*)d_in[2];
  const float* bias = (const float*)d_in[3];
  float* out  = (float*)d_out;
  short* ap   = (short*)d_ws;   // 24*256*32*2 = 393216 B of scratch

  // pack weights (runs each call; deterministic, ~3 us)
  pack_weights_kernel<<<dim3((NQ * COUT * 32 / 2 + 255) / 256), dim3(256), 0, stream>>>(wgt, ap);
  // 8 batches x 64 t-tiles = 512 blocks (2/CU), 512 threads (8 waves)
  deform_gemm_kernel<<<dim3(512), dim3(512), 0, stream>>>(x, off, ap, bias, out);
}